// Round 4
// baseline (1345.802 us; speedup 1.0000x reference)
//
#include <hip/hip_runtime.h>
#include <hip/hip_bf16.h>
#include <math.h>

#define T_FRAMES 65536
#define FSTRIDE  345          // 115 points * 3 coords (float32 elements)
#define NB1      16384        // phase-1 blocks (4 frames each)
#define NB3      100          // phase-3 blocks (1 output row each)

// invert triu(k=1) linear index l -> (a,b) for an N-point set; <=N iterations
__device__ __forceinline__ void triu_ab(int l, int N, int& a, int& b) {
  int a0 = 0, rem = l, row = N - 1;
  while (rem >= row) { rem -= row; ++a0; --row; }
  a = a0; b = a0 + 1 + rem;
}

// ws layout: ctrl[0]=ticket ctrl[1]=flag ctrl[2]=cond (first 16 B zeroed by
// hipMemsetAsync each launch); order[104] at +16; keepF[65536] uchar2 at +512.
__global__ __launch_bounds__(256) void fused(const float* __restrict__ x,
                                             unsigned* __restrict__ ctrl,
                                             int* __restrict__ order,
                                             uchar2* __restrict__ keepF,
                                             float* __restrict__ out) {
  const int bid  = blockIdx.x;
  const int tid  = threadIdx.x;
  const int lane = tid & 63;
  const int wv   = tid >> 6;

  if (bid < NB1) {
    // ================= phase 1: per-frame keep-bit + nonzero count ==========
    const int f = (bid << 2) + wv;
    const float* xf = x + (size_t)f * FSTRIDE;
    float vl = 0.f, vr = 0.f; int cl = 0, cr = 0;
    if (lane < 63) {
      float a = xf[120 + lane]; if (isnan(a)) a = 0.f;  // left hand: pts 40..60
      float b = xf[282 + lane]; if (isnan(b)) b = 0.f;  // right hand: pts 94..114
      vl = a; vr = b; cl = (a != 0.f); cr = (b != 0.f);
    }
    for (int off = 32; off > 0; off >>= 1) {
      vl += __shfl_down(vl, off, 64);
      vr += __shfl_down(vr, off, 64);
      cl += __shfl_down(cl, off, 64);
      cr += __shfl_down(cr, off, 64);
    }
    if (lane == 0) {
      uchar2 k;
      k.x = (unsigned char)(cl | ((vl != 0.f) ? 0x80 : 0));
      k.y = (unsigned char)(cr | ((vr != 0.f) ? 0x80 : 0));
      keepF[f] = k;
    }
    __threadfence();              // release keepF stores to device scope
    __syncthreads();
    __shared__ unsigned sLast;
    if (tid == 0) sLast = (atomicAdd(&ctrl[0], 1u) == NB1 - 1) ? 1u : 0u;
    __syncthreads();
    if (!sLast) return;
    __threadfence();              // acquire: all other blocks' keepF now visible

    // ================= phase 2 (last block only, 256 threads) ===============
    __shared__ int sL[4], sR[4];
    __shared__ unsigned long long sM[4];
    __shared__ int sBase, sCond;

    // totals: sum 7-bit counts, vectorized as uint4 (16 B = 8 frames)
    const uint4* kp = (const uint4*)keepF;          // 8192 uint4 total
    int tl = 0, tr = 0;
    #pragma unroll 4
    for (int i = tid; i < (T_FRAMES * 2 / 16); i += 256) {
      uint4 v = kp[i];
      unsigned t;  // bytes per uint: [f.x, f.y, f+1.x, f+1.y]
      t = v.x & 0x7F7F7F7Fu; tl += (t & 0xFF) + ((t >> 16) & 0xFF); tr += ((t >> 8) & 0xFF) + ((t >> 24) & 0xFF);
      t = v.y & 0x7F7F7F7Fu; tl += (t & 0xFF) + ((t >> 16) & 0xFF); tr += ((t >> 8) & 0xFF) + ((t >> 24) & 0xFF);
      t = v.z & 0x7F7F7F7Fu; tl += (t & 0xFF) + ((t >> 16) & 0xFF); tr += ((t >> 8) & 0xFF) + ((t >> 24) & 0xFF);
      t = v.w & 0x7F7F7F7Fu; tl += (t & 0xFF) + ((t >> 16) & 0xFF); tr += ((t >> 8) & 0xFF) + ((t >> 24) & 0xFF);
    }
    for (int off = 32; off > 0; off >>= 1) {
      tl += __shfl_down(tl, off, 64);
      tr += __shfl_down(tr, off, 64);
    }
    if (lane == 0) { sL[wv] = tl; sR[wv] = tr; }
    __syncthreads();
    if (tid == 0) {
      int L = sL[0] + sL[1] + sL[2] + sL[3];
      int R = sR[0] + sR[1] + sR[2] + sR[3];
      sCond = (L > R) ? 1 : 0;
      ctrl[2] = (unsigned)sCond;
      sBase = 0;
    }
    __syncthreads();
    const int cond = sCond;

    // stable partition: keep-first (pass 0), then non-keep (pass 1); need 101
    for (int pass = 0; pass < 2; ++pass) {
      for (int base = 0; base < T_FRAMES; base += 256) {
        if (sBase >= 101) break;               // uniform; barrier-stable
        uchar2 k = keepF[base + tid];
        int fl = ((cond ? (int)k.x : (int)k.y) >> 7) & 1;
        if (pass) fl ^= 1;
        unsigned long long m = __ballot(fl);
        if (lane == 0) sM[wv] = m;
        __syncthreads();
        int pos = sBase;
        for (int w = 0; w < wv; ++w) pos += (int)__popcll(sM[w]);
        pos += (int)__popcll(m & ((1ull << lane) - 1ull));
        if (fl && pos < 101) order[pos] = base + tid;
        __syncthreads();
        if (tid == 0) {
          sBase += (int)(__popcll(sM[0]) + __popcll(sM[1]) + __popcll(sM[2]) + __popcll(sM[3]));
        }
        __syncthreads();
      }
    }

    __threadfence();              // release order/cond
    __syncthreads();
    if (tid == 0)
      __hip_atomic_store(&ctrl[1], 1u, __ATOMIC_RELEASE, __HIP_MEMORY_SCOPE_AGENT);
    return;
  }

  // ================= phase 3: one output row per block =====================
  if (tid == 0) {
    while (__hip_atomic_load(&ctrl[1], __ATOMIC_ACQUIRE, __HIP_MEMORY_SCOPE_AGENT) == 0u)
      __builtin_amdgcn_s_sleep(8);
  }
  __syncthreads();

  __shared__ float A[258], B[258];   // xfeat (86 pts x 3) for frames order[row], order[row+1]
  const int row  = bid - NB1;
  const int cond = (int)ctrl[2];
  const int f = order[row], g = order[row + 1];
  const float* xf = x + (size_t)f * FSTRIDE;
  const float* xg = x + (size_t)g * FSTRIDE;

  for (int idx = tid; idx < 258; idx += blockDim.x) {
    const int p = idx / 3, c = idx - p * 3;
    // xfeat point -> source point in x: hand(21) | pose(25) | lip(40)
    const int s = (p < 21) ? (cond ? 40 + p : 94 + p) : ((p < 46) ? p + 40 : p - 46);
    float va = xf[s * 3 + c]; if (isnan(va)) va = 0.f;
    float vb = xg[s * 3 + c]; if (isnan(vb)) vb = 0.f;
    if (cond && c == 0) { va = -va; vb = -vb; }   // xc negation applies to all 86 points
    A[idx] = va; B[idx] = vb;
  }
  __syncthreads();

  float* o = out + (size_t)row * 1196;
  for (int j = tid; j < 1196; j += blockDim.x) {
    float v;
    if (j < 306) {                       // positional: xfeat (153) then dxyz (153)
      int jj = j; bool diff = false;
      if (jj >= 153) { diff = true; jj -= 153; }
      int p, c;
      if (jj < 63)       { p = jj / 3;             c = jj - p * 3; }
      else if (jj < 113) { int t = jj - 63;  p = 21 + (t >> 1); c = t & 1; }
      else               { int t = jj - 113; p = 46 + (t >> 1); c = t & 1; }
      v = A[p * 3 + c];
      if (diff) v -= B[p * 3 + c];
    } else if (j < 516) {                // hdist: 21 pts, 3D, 210 pairs
      int a, b; triu_ab(j - 306, 21, a, b);
      const float dx = A[a*3]   - A[b*3];
      const float dy = A[a*3+1] - A[b*3+1];
      const float dz = A[a*3+2] - A[b*3+2];
      v = sqrtf(dx*dx + dy*dy + dz*dz);
    } else if (j < 816) {                // pdist: pose 25 pts, 2D, 300 pairs
      int a, b; triu_ab(j - 516, 25, a, b);
      a += 21; b += 21;
      const float dx = A[a*3] - A[b*3], dy = A[a*3+1] - A[b*3+1];
      v = sqrtf(dx*dx + dy*dy);
    } else if (j < 1006) {               // oldist: lip pts 46..65, 2D, 190 pairs
      int a, b; triu_ab(j - 816, 20, a, b);
      a += 46; b += 46;
      const float dx = A[a*3] - A[b*3], dy = A[a*3+1] - A[b*3+1];
      v = sqrtf(dx*dx + dy*dy);
    } else {                             // ildist: lip pts 66..85, 2D, 190 pairs
      int a, b; triu_ab(j - 1006, 20, a, b);
      a += 66; b += 66;
      const float dx = A[a*3] - A[b*3], dy = A[a*3+1] - A[b*3+1];
      v = sqrtf(dx*dx + dy*dy);
    }
    o[j] = v;
  }
}

extern "C" void kernel_launch(void* const* d_in, const int* in_sizes, int n_in,
                              void* d_out, int out_size, void* d_ws, size_t ws_size,
                              hipStream_t stream) {
  const float* x = (const float*)d_in[0];
  float* out = (float*)d_out;
  char* ws = (char*)d_ws;
  // ws layout:
  //   [0,16)        unsigned ctrl[4]: ticket, flag, cond, pad  (memset to 0)
  //   [16,432)      int      order[104]
  //   [512,131584)  uchar2   keepF[65536]   (128 KB)
  unsigned* ctrl  = (unsigned*)ws;
  int*      order = (int*)(ws + 16);
  uchar2*   keepF = (uchar2*)(ws + 512);

  hipMemsetAsync(ctrl, 0, 16, stream);   // known-zero ticket/flag under 0xAA poison
  fused<<<NB1 + NB3, 256, 0, stream>>>(x, ctrl, order, keepF, out);
}

// Round 5
// 136.755 us; speedup vs baseline: 9.8410x; 9.8410x over previous
//
#include <hip/hip_runtime.h>
#include <hip/hip_bf16.h>
#include <math.h>

#define T_FRAMES 65536
#define FSTRIDE  345          // 115 points * 3 coords (float32 elements)

// invert triu(k=1) linear index l -> (a,b) for an N-point set; <=N iterations
__device__ __forceinline__ void triu_ab(int l, int N, int& a, int& b) {
  int a0 = 0, rem = l, row = N - 1;
  while (rem >= row) { rem -= row; ++a0; --row; }
  a = a0; b = a0 + 1 + rem;
}

// ---- phase 1: per-frame packed {nonzero-count (7b) | keep-bit (bit7)} ------
// One wave (64 lanes) per frame; lanes 0..62 read the 63 floats of each hand.
__global__ __launch_bounds__(256) void phase1(const float* __restrict__ x,
                                              uchar2* __restrict__ keepF) {
  const int wave = threadIdx.x >> 6;
  const int lane = threadIdx.x & 63;
  const int f = (blockIdx.x << 2) + wave;
  const float* xf = x + (size_t)f * FSTRIDE;
  float vl = 0.f, vr = 0.f; int cl = 0, cr = 0;
  if (lane < 63) {
    float a = xf[120 + lane]; if (isnan(a)) a = 0.f;  // left hand: pts 40..60
    float b = xf[282 + lane]; if (isnan(b)) b = 0.f;  // right hand: pts 94..114
    vl = a; vr = b; cl = (a != 0.f); cr = (b != 0.f);
  }
  for (int off = 32; off > 0; off >>= 1) {
    vl += __shfl_down(vl, off, 64);
    vr += __shfl_down(vr, off, 64);
    cl += __shfl_down(cl, off, 64);
    cr += __shfl_down(cr, off, 64);
  }
  if (lane == 0) {
    uchar2 k;
    k.x = (unsigned char)(cl | ((vl != 0.f) ? 0x80 : 0));
    k.y = (unsigned char)(cr | ((vr != 0.f) ? 0x80 : 0));
    keepF[f] = k;
  }
}

// ---- phase 2+3 merged: each of the 100 blocks redundantly computes cond +
// the first-101 stable order (LDS), then emits its output row. No fences, no
// spin — keepF visibility comes from the kernel boundary.
__global__ __launch_bounds__(256) void phase23(const float* __restrict__ x,
                                               const uchar2* __restrict__ keepF,
                                               float* __restrict__ out) {
  const int tid  = threadIdx.x;
  const int lane = tid & 63;
  const int wv   = tid >> 6;
  __shared__ int sL[4], sR[4];
  __shared__ unsigned long long sM[4];
  __shared__ int sOrder[104];
  __shared__ int sBase, sCond;

  // ---- cond: sum 7-bit counts, vectorized as uint4 (16 B = 8 frames) ----
  const uint4* kp = (const uint4*)keepF;          // 8192 uint4 total
  int tl = 0, tr = 0;
  #pragma unroll 4
  for (int i = tid; i < (T_FRAMES * 2 / 16); i += 256) {
    uint4 v = kp[i];
    unsigned t;  // bytes per uint: [f.x, f.y, f+1.x, f+1.y] -> left bytes 0,2; right 1,3
    t = v.x & 0x7F7F7F7Fu; tl += (t & 0xFF) + ((t >> 16) & 0xFF); tr += ((t >> 8) & 0xFF) + ((t >> 24) & 0xFF);
    t = v.y & 0x7F7F7F7Fu; tl += (t & 0xFF) + ((t >> 16) & 0xFF); tr += ((t >> 8) & 0xFF) + ((t >> 24) & 0xFF);
    t = v.z & 0x7F7F7F7Fu; tl += (t & 0xFF) + ((t >> 16) & 0xFF); tr += ((t >> 8) & 0xFF) + ((t >> 24) & 0xFF);
    t = v.w & 0x7F7F7F7Fu; tl += (t & 0xFF) + ((t >> 16) & 0xFF); tr += ((t >> 8) & 0xFF) + ((t >> 24) & 0xFF);
  }
  for (int off = 32; off > 0; off >>= 1) {
    tl += __shfl_down(tl, off, 64);
    tr += __shfl_down(tr, off, 64);
  }
  if (lane == 0) { sL[wv] = tl; sR[wv] = tr; }
  __syncthreads();
  if (tid == 0) {
    int L = sL[0] + sL[1] + sL[2] + sL[3];
    int R = sR[0] + sR[1] + sR[2] + sR[3];
    sCond = (L > R) ? 1 : 0;
    sBase = 0;
  }
  __syncthreads();
  const int cond = sCond;

  // ---- stable partition: keep-first (pass 0) then non-keep (pass 1); need 101.
  // Early-exit: for this data keep is all-true -> one 256-frame tile suffices.
  for (int pass = 0; pass < 2; ++pass) {
    for (int base = 0; base < T_FRAMES; base += 256) {
      if (sBase >= 101) break;               // uniform; barrier-stable
      uchar2 k = keepF[base + tid];
      int fl = ((cond ? (int)k.x : (int)k.y) >> 7) & 1;
      if (pass) fl ^= 1;
      unsigned long long m = __ballot(fl);
      if (lane == 0) sM[wv] = m;
      __syncthreads();
      int pos = sBase;
      for (int w = 0; w < wv; ++w) pos += (int)__popcll(sM[w]);
      pos += (int)__popcll(m & ((1ull << lane) - 1ull));
      if (fl && pos < 101) sOrder[pos] = base + tid;
      __syncthreads();
      if (tid == 0)
        sBase += (int)(__popcll(sM[0]) + __popcll(sM[1]) + __popcll(sM[2]) + __popcll(sM[3]));
      __syncthreads();
    }
    if (sBase >= 101) break;
  }
  __syncthreads();

  // ---- phase 3 proper: one output row for this block ----
  __shared__ float A[258], B[258];   // xfeat (86 pts x 3) for frames sOrder[row], sOrder[row+1]
  const int row = blockIdx.x;
  const int f = sOrder[row], g = sOrder[row + 1];
  const float* xf = x + (size_t)f * FSTRIDE;
  const float* xg = x + (size_t)g * FSTRIDE;

  for (int idx = tid; idx < 258; idx += blockDim.x) {
    const int p = idx / 3, c = idx - p * 3;
    // xfeat point -> source point in x: hand(21) | pose(25) | lip(40)
    const int s = (p < 21) ? (cond ? 40 + p : 94 + p) : ((p < 46) ? p + 40 : p - 46);
    float va = xf[s * 3 + c]; if (isnan(va)) va = 0.f;
    float vb = xg[s * 3 + c]; if (isnan(vb)) vb = 0.f;
    if (cond && c == 0) { va = -va; vb = -vb; }   // xc negation applies to all 86 points
    A[idx] = va; B[idx] = vb;
  }
  __syncthreads();

  float* o = out + (size_t)row * 1196;
  for (int j = tid; j < 1196; j += blockDim.x) {
    float v;
    if (j < 306) {                       // positional: xfeat (153) then dxyz (153)
      int jj = j; bool diff = false;
      if (jj >= 153) { diff = true; jj -= 153; }
      int p, c;
      if (jj < 63)       { p = jj / 3;             c = jj - p * 3; }
      else if (jj < 113) { int t = jj - 63;  p = 21 + (t >> 1); c = t & 1; }
      else               { int t = jj - 113; p = 46 + (t >> 1); c = t & 1; }
      v = A[p * 3 + c];
      if (diff) v -= B[p * 3 + c];
    } else if (j < 516) {                // hdist: 21 pts, 3D, 210 pairs
      int a, b; triu_ab(j - 306, 21, a, b);
      const float dx = A[a*3]   - A[b*3];
      const float dy = A[a*3+1] - A[b*3+1];
      const float dz = A[a*3+2] - A[b*3+2];
      v = sqrtf(dx*dx + dy*dy + dz*dz);
    } else if (j < 816) {                // pdist: pose 25 pts, 2D, 300 pairs
      int a, b; triu_ab(j - 516, 25, a, b);
      a += 21; b += 21;
      const float dx = A[a*3] - A[b*3], dy = A[a*3+1] - A[b*3+1];
      v = sqrtf(dx*dx + dy*dy);
    } else if (j < 1006) {               // oldist: lip pts 46..65, 2D, 190 pairs
      int a, b; triu_ab(j - 816, 20, a, b);
      a += 46; b += 46;
      const float dx = A[a*3] - A[b*3], dy = A[a*3+1] - A[b*3+1];
      v = sqrtf(dx*dx + dy*dy);
    } else {                             // ildist: lip pts 66..85, 2D, 190 pairs
      int a, b; triu_ab(j - 1006, 20, a, b);
      a += 66; b += 66;
      const float dx = A[a*3] - A[b*3], dy = A[a*3+1] - A[b*3+1];
      v = sqrtf(dx*dx + dy*dy);
    }
    o[j] = v;
  }
}

extern "C" void kernel_launch(void* const* d_in, const int* in_sizes, int n_in,
                              void* d_out, int out_size, void* d_ws, size_t ws_size,
                              hipStream_t stream) {
  const float* x = (const float*)d_in[0];
  float* out = (float*)d_out;
  char* ws = (char*)d_ws;
  // ws layout: keepF[65536] uchar2 at +512 (fully written by phase1 each launch)
  uchar2* keepF = (uchar2*)(ws + 512);

  phase1<<<T_FRAMES / 4, 256, 0, stream>>>(x, keepF);
  phase23<<<100, 256, 0, stream>>>(x, keepF, out);
}